// Round 5
// baseline (851.777 us; speedup 1.0000x reference)
//
#include <hip/hip_runtime.h>

// Problem constants
#define B_ 256
#define L_ 196
#define C_ 768
#define K_ 2048
#define BL_ 50176  // B_*L_

typedef __attribute__((ext_vector_type(8))) short bf16x8;
typedef __attribute__((ext_vector_type(4))) float f32x4;

typedef const __attribute__((address_space(1))) void gas_void;
typedef __attribute__((address_space(3))) void las_void;

__device__ __forceinline__ unsigned short f2bf(float f) {
  unsigned u = __builtin_bit_cast(unsigned, f);
  u = u + 0x7FFFu + ((u >> 16) & 1u);  // RNE, no NaN inputs
  return (unsigned short)(u >> 16);
}

// monotone map: float bits -> unsigned with total order (handles negatives)
__device__ __forceinline__ unsigned fmono(float f) {
  unsigned u = __builtin_bit_cast(unsigned, f);
  return u ^ ((unsigned)((int)u >> 31) | 0x80000000u);
}

// ---------------------------------------------------------------------------
// Kernel P: per-code precompute: cbb bf16 [K][C], norms64/32, ac.
// ---------------------------------------------------------------------------
__global__ __launch_bounds__(256) void precompute_kernel(
    const float* __restrict__ cb, const float* __restrict__ attw,
    unsigned short* __restrict__ cbb, double* __restrict__ norms64,
    float* __restrict__ norms32, float* __restrict__ ac) {
  int wave = threadIdx.x >> 6;
  int lane = threadIdx.x & 63;
  int k = blockIdx.x * 4 + wave;
  const float* row = cb + (size_t)k * C_;
  double n = 0.0, a = 0.0;
  for (int c = lane; c < C_; c += 64) {
    float v = row[c];
    cbb[(size_t)k * C_ + c] = f2bf(v);
    n = fma((double)v, (double)v, n);
    a = fma((double)v, (double)attw[c * 3 + 1], a);
  }
  for (int off = 32; off > 0; off >>= 1) {
    n += __shfl_down(n, off);
    a += __shfl_down(a, off);
  }
  if (lane == 0) {
    norms64[k] = n;
    norms32[k] = (float)n;
    ac[k] = (a > 0.0) ? (float)a : 0.0f;
  }
}

// ---------------------------------------------------------------------------
// Kernel X: convert in_feas f32 -> bf16 xb [BL][C]. 9633792 float4 groups.
// ---------------------------------------------------------------------------
__global__ __launch_bounds__(256) void convert_kernel(
    const float* __restrict__ x, unsigned short* __restrict__ xb) {
  int i = blockIdx.x * 256 + threadIdx.x;  // exact: 37632*256 = BL_*C_/4
  float4 v = ((const float4*)x)[i];
  uint2 w;
  w.x = (unsigned)f2bf(v.x) | ((unsigned)f2bf(v.y) << 16);
  w.y = (unsigned)f2bf(v.z) | ((unsigned)f2bf(v.w) << 16);
  ((uint2*)xb)[i] = w;
}

// ---------------------------------------------------------------------------
// Phase 1 (v5): 256x256 tile, BK=64, 512 threads = 8 waves (2M x 4N).
// REG-STAGED double buffer (global_load_dwordx4 -> VGPR -> ds_write_b128),
// replacing global_load_lds DMA. Rationale (R2-R4 post-mortems): v2/v3/v4
// (1/8/3 barriers, counted vmcnt) all pinned at 308-310us with identical
// profiles; the invariant is 768 global_load_lds wave-instrs per block at
// ~156 cyc each = the whole 120k-cycle block span -- the LDS-DMA path
// behaves ~serialized at one L2 round-trip per instruction. Register loads
// pipeline (vmcnt up to 63 outstanding): issue 8 loads/thread at tile
// start, ds_write them to the other buffer mid/end-of-tile (compiler
// auto-inserts counted vmcnt before each write), ONE barrier per K-tile.
// Hazard ledger: reads(buf)@t vs writes(buf)@t+1 sealed by t's barrier;
// writes(buf^1)@t vs reads(buf^1)@t+1 sealed (lgkm drained) by same
// barrier; same-tile reads/writes touch disjoint buffers.
// Fragment loads restructured to af[4]+bfr[2] live (24 regs) so total
// unified regs ~230 keeps 2 waves/SIMD (pool ~512/SIMD).
// XOR slot swizzle now applied at ds_write time (write chunk (row, slotpos)
// receives global slot slotpos^(row&7)); reads unchanged from v4
// (verified: conflicts == 0).
// Block mapping: 8 consecutive blocks on an XCD share mblk across the 8
// code panels -> xb tile L2-reused 8x; cbb L2-resident (verified R3:
// FETCH 312->113 MB).
// ---------------------------------------------------------------------------
__global__ __launch_bounds__(512, 2) void phase1_kernel(
    const unsigned short* __restrict__ xb,
    const unsigned short* __restrict__ cbb,
    const float* __restrict__ norms32, unsigned* __restrict__ ws_cand) {
  // [buf][op(0=A,1=B)][half][128*64] bf16 = 128 KB
  __shared__ unsigned short lds[2][2][2][128 * 64];
  __shared__ float norms_s[256];
  __shared__ unsigned cands_s[256][12];

  int tid = threadIdx.x;
  int bid = blockIdx.x;
  // token-tile-shared-per-XCD mapping (see header comment)
  int x8 = bid & 7, m = bid >> 3;
  int mblk, nblk;
  if (m < 192) {
    mblk = (m & ~7) | x8;  // 8 consecutive blocks on an XCD share mblk
    nblk = m & 7;
  } else {
    mblk = m;  // 192..195
    nblk = x8;
  }
  size_t row0 = (size_t)mblk * 256;
  int code0 = nblk * 256;

  int wv = tid >> 6, l = tid & 63;
  int wm = wv >> 2, wn = wv & 3;  // 2 x 4 wave grid
  int col16 = l & 15, quad = l >> 4;

  if (tid < 256) norms_s[tid] = norms32[code0 + tid];

  // staging geometry: half-tile = 128 rows x 64 cols bf16 = 16 KB = 1024
  // 16B chunks; thread tid owns chunks {tid, tid+512} -> LDS bytes
  // {tid*16 + i*8192}. chunk c: row = c>>3 = i*64 + (tid>>3), slotpos =
  // tid&7; source slot XOR-swizzled: slotraw = slotpos ^ (row&7).
  int slotraw = (tid & 7) ^ ((tid >> 3) & 7);
  const unsigned short* abase = xb + (row0 + (tid >> 3)) * (size_t)C_ +
                                (size_t)slotraw * 8;
  const unsigned short* bbase = cbb + ((size_t)code0 + (tid >> 3)) * C_ +
                                (size_t)slotraw * 8;

  uint4 aA[2][2], bB[2][2];  // [half][i] staged chunks (16+16 regs)
  auto issueA = [&](int kt) {
#pragma unroll
    for (int h = 0; h < 2; ++h)
#pragma unroll
      for (int i = 0; i < 2; ++i)
        aA[h][i] = *(const uint4*)(abase + (size_t)h * 128 * C_ +
                                   (size_t)i * 64 * C_ + kt * 64);
  };
  auto issueB = [&](int kt) {
#pragma unroll
    for (int h = 0; h < 2; ++h)
#pragma unroll
      for (int i = 0; i < 2; ++i)
        bB[h][i] = *(const uint4*)(bbase + (size_t)h * 128 * C_ +
                                   (size_t)i * 64 * C_ + kt * 64);
  };
  auto writeA = [&](int wb) {
#pragma unroll
    for (int h = 0; h < 2; ++h)
#pragma unroll
      for (int i = 0; i < 2; ++i)
        *(uint4*)((char*)&lds[wb][0][h][0] + i * 8192 + (size_t)tid * 16) =
            aA[h][i];
  };
  auto writeB = [&](int wb) {
#pragma unroll
    for (int h = 0; h < 2; ++h)
#pragma unroll
      for (int i = 0; i < 2; ++i)
        *(uint4*)((char*)&lds[wb][1][h][0] + i * 8192 + (size_t)tid * 16) =
            bB[h][i];
  };

  f32x4 acc[2][2][4][2];  // [mh][nh][mt][nt]
#pragma unroll
  for (int mh = 0; mh < 2; ++mh)
#pragma unroll
    for (int nh = 0; nh < 2; ++nh)
#pragma unroll
      for (int mt = 0; mt < 4; ++mt)
#pragma unroll
        for (int nt = 0; nt < 2; ++nt)
          acc[mh][nh][mt][nt] = (f32x4){0.f, 0.f, 0.f, 0.f};

  bf16x8 af[4], bfr[2];

#define LOADA(mh, ks)                                                       \
  _Pragma("unroll") for (int mt = 0; mt < 4; ++mt) af[mt] =                 \
      *(const bf16x8*)((const char*)&lds[buf][0][mh][0] +                   \
                       (wm * 64 + mt * 16 + col16) * 128 +                  \
                       ((((ks)*4 + quad) ^ (col16 & 7)) * 16));

#define LOADB(nh, ks)                                                       \
  _Pragma("unroll") for (int nt = 0; nt < 2; ++nt) bfr[nt] =                \
      *(const bf16x8*)((const char*)&lds[buf][1][nh][0] +                   \
                       (wn * 32 + nt * 16 + col16) * 128 +                  \
                       ((((ks)*4 + quad) ^ (col16 & 7)) * 16));

#define MFMA8(mh, nh)                                                       \
  _Pragma("unroll") for (int mt = 0; mt < 4; ++mt)                          \
      _Pragma("unroll") for (int nt = 0; nt < 2; ++nt)                      \
          acc[mh][nh][mt][nt] = __builtin_amdgcn_mfma_f32_16x16x32_bf16(    \
              af[mt], bfr[nt], acc[mh][nh][mt][nt], 0, 0, 0);

  // Prologue: stage tile 0 through registers.
  issueA(0);
  issueB(0);
  writeA(0);
  writeB(0);
  __syncthreads();

  for (int t = 0; t < 12; ++t) {
    int buf = t & 1;
    bool st = (t < 11);
    if (st) {
      issueA(t + 1);  // 8 global_load_dwordx4 in flight across the tile
      issueB(t + 1);
    }
    // mh = 0 half (32 MFMAs)
    LOADA(0, 0);
    LOADB(0, 0);
    MFMA8(0, 0);
    LOADB(1, 0);
    MFMA8(0, 1);
    LOADA(0, 1);
    LOADB(0, 1);
    MFMA8(0, 0);
    LOADB(1, 1);
    MFMA8(0, 1);
    if (st) writeA(buf ^ 1);  // compiler inserts counted vmcnt before writes
    // mh = 1 half (32 MFMAs)
    LOADA(1, 0);
    LOADB(0, 0);
    MFMA8(1, 0);
    LOADB(1, 0);
    MFMA8(1, 1);
    LOADA(1, 1);
    LOADB(0, 1);
    MFMA8(1, 0);
    LOADB(1, 1);
    MFMA8(1, 1);
    if (st) writeB(buf ^ 1);
    __syncthreads();  // seals buffer transition (vmem+lds drained)
  }

#undef LOADA
#undef LOADB
#undef MFMA8

  // epilogue: top-3 per token within this wave's 64 codes (4x16 over nh,nt)
#pragma unroll
  for (int mh = 0; mh < 2; ++mh) {
#pragma unroll
    for (int mt = 0; mt < 4; ++mt) {
#pragma unroll
      for (int r = 0; r < 4; ++r) {
        unsigned keys[4];
#pragma unroll
        for (int nh = 0; nh < 2; ++nh)
#pragma unroll
          for (int nt = 0; nt < 2; ++nt) {
            int codel = nh * 128 + wn * 32 + nt * 16 + col16;
            float d = fmaf(-2.0f, acc[mh][nh][mt][nt][r], norms_s[codel]);
            keys[nh * 2 + nt] =
                (fmono(d) & 0xFFFFF800u) | (unsigned)(code0 + codel);
          }
        unsigned win[3];
#pragma unroll
        for (int rnd = 0; rnd < 3; ++rnd) {
          unsigned mn = min(min(keys[0], keys[1]), min(keys[2], keys[3]));
          mn = min(mn, (unsigned)__shfl_xor((int)mn, 1));
          mn = min(mn, (unsigned)__shfl_xor((int)mn, 2));
          mn = min(mn, (unsigned)__shfl_xor((int)mn, 4));
          mn = min(mn, (unsigned)__shfl_xor((int)mn, 8));
          win[rnd] = mn;
#pragma unroll
          for (int nt = 0; nt < 4; ++nt)
            if (keys[nt] == mn) keys[nt] = 0xFFFFFFFFu;
        }
        if (col16 == 0) {
          int t = mh * 128 + wm * 64 + mt * 16 + quad * 4 + r;
          cands_s[t][wn * 3 + 0] = win[0];
          cands_s[t][wn * 3 + 1] = win[1];
          cands_s[t][wn * 3 + 2] = win[2];
        }
      }
    }
  }
  __syncthreads();
  for (int i = tid; i < 256 * 12; i += 512) {
    int t = i / 12;
    int j = i - t * 12;
    ws_cand[(row0 + t) * 96 + nblk * 12 + j] = cands_s[t][j];
  }
}

// ---------------------------------------------------------------------------
// Phase 2 (v2): per token, top-6 of 96 approx keys -> exact f64 rescore.
// 768 threads/block, 32 tokens: each (token,code) dot computed by a 4-lane
// group (48 coalesced float4 loads + 192 f64 FMA per lane + shfl reduce)
// instead of 1 thread per dot (was: serial 768-FMA chain + scattered reads).
// ---------------------------------------------------------------------------
__global__ __launch_bounds__(768) void phase2_kernel(
    const float* __restrict__ x, const float* __restrict__ cb,
    const unsigned* __restrict__ ws_cand, const double* __restrict__ norms64,
    int* __restrict__ out_idx) {
  __shared__ unsigned cl[32][100];  // pad 96->100 (bank spread)
  __shared__ int rcode[32][6];
  __shared__ double rd[32][6];
  int tid = threadIdx.x;
  size_t tok0 = (size_t)blockIdx.x * 32;

  for (int i = tid; i < 32 * 96; i += 768) {
    int t = i / 96;
    int s = i - t * 96;
    cl[t][s] = ws_cand[tok0 * 96 + i];
  }
  __syncthreads();

  if (tid < 32) {
    unsigned best[6];
#pragma unroll
    for (int j = 0; j < 6; ++j) best[j] = 0xFFFFFFFFu;
    for (int s = 0; s < 96; ++s) {
      unsigned v = cl[tid][s];
      if (v < best[5]) {
        best[5] = v;
#pragma unroll
        for (int j = 5; j > 0; --j) {
          if (best[j] < best[j - 1]) {
            unsigned t = best[j];
            best[j] = best[j - 1];
            best[j - 1] = t;
          }
        }
      }
    }
#pragma unroll
    for (int j = 0; j < 6; ++j) rcode[tid][j] = (int)(best[j] & 0x7FFu);
  }
  __syncthreads();

  {
    int g = tid >> 2;       // dot id 0..191
    int j = tid & 3;        // lane within 4-group
    int t = g / 6;
    int jc = g - t * 6;
    int code = rcode[t][jc];
    const float* xr = x + (tok0 + t) * (size_t)C_;
    const float* cr = cb + (size_t)code * C_;
    double s = 0.0;
#pragma unroll 4
    for (int mm = 0; mm < 48; ++mm) {
      int e = j * 4 + mm * 16;  // lane j covers float4 indices j, j+4, ...
      float4 xa = *(const float4*)(xr + e);
      float4 ca = *(const float4*)(cr + e);
      s = fma((double)xa.x, (double)ca.x, s);
      s = fma((double)xa.y, (double)ca.y, s);
      s = fma((double)xa.z, (double)ca.z, s);
      s = fma((double)xa.w, (double)ca.w, s);
    }
    s += __shfl_xor(s, 1);
    s += __shfl_xor(s, 2);
    if (j == 0) rd[t][jc] = fma(-2.0, s, norms64[code]);
  }
  __syncthreads();

  if (tid < 32) {
    double bv = rd[tid][0];
    int bi = rcode[tid][0];
#pragma unroll
    for (int j = 1; j < 6; ++j) {
      double v = rd[tid][j];
      int i0 = rcode[tid][j];
      if (v < bv || (v == bv && i0 < bi)) {
        bv = v;
        bi = i0;
      }
    }
    out_idx[tok0 + tid] = bi;
  }
}

// ---------------------------------------------------------------------------
// Fallback argmin (round-2 kernel) if ws_size is too small for phase 1/2.
// ---------------------------------------------------------------------------
#define APAD 776
__global__ __launch_bounds__(256, 2) void argmin_fallback(
    const float* __restrict__ x, const float* __restrict__ cb,
    const unsigned short* __restrict__ cbb,
    const double* __restrict__ norms64, const float* __restrict__ norms32,
    int* __restrict__ out_idx) {
  __shared__ unsigned short Asf[32 * APAD];
  __shared__ float norms_s[K_];
  __shared__ unsigned int cands[32][48];
  __shared__ int rcode[32][6];
  __shared__ double rd[32][6];

  int tid = threadIdx.x;
  size_t tok0 = (size_t)blockIdx.x * 32;

  for (int i = tid; i < K_; i += 256) norms_s[i] = norms32[i];

  const float4* xin = (const float4*)(x + tok0 * C_);
  for (int i = tid; i < 32 * 192; i += 256) {
    int tok = i / 192;
    int c4 = i - tok * 192;
    float4 v = xin[i];
    uint2 w;
    w.x = (unsigned)f2bf(v.x) | ((unsigned)f2bf(v.y) << 16);
    w.y = (unsigned)f2bf(v.z) | ((unsigned)f2bf(v.w) << 16);
    *(uint2*)&Asf[tok * APAD + c4 * 4] = w;
  }
  __syncthreads();

  int wv = tid >> 6;
  int lane = tid & 63;
  int col = lane & 15;
  int quad = lane >> 4;

  const unsigned short* a0p = &Asf[(col)*APAD + quad * 8];
  const unsigned short* a1p = &Asf[(16 + col) * APAD + quad * 8];

  for (int chunk = 0; chunk < 4; ++chunk) {
    int code0 = chunk * 512 + wv * 128 + col;
    const unsigned short* bbase = cbb + (size_t)code0 * C_ + quad * 8;

    f32x4 acc[2][8];
#pragma unroll
    for (int m = 0; m < 2; ++m)
#pragma unroll
      for (int n = 0; n < 8; ++n) acc[m][n] = (f32x4){0.f, 0.f, 0.f, 0.f};

    bf16x8 ca0 = *(const bf16x8*)(a0p);
    bf16x8 ca1 = *(const bf16x8*)(a1p);
    bf16x8 cbf[8];
#pragma unroll
    for (int n = 0; n < 8; ++n)
      cbf[n] = *(const bf16x8*)(bbase + (size_t)n * 16 * C_);

    for (int ks = 0; ks < 24; ++ks) {
      bf16x8 na0, na1, nbf[8];
      if (ks < 23) {
        int k1 = (ks + 1) * 32;
        na0 = *(const bf16x8*)(a0p + k1);
        na1 = *(const bf16x8*)(a1p + k1);
#pragma unroll
        for (int n = 0; n < 8; ++n)
          nbf[n] = *(const bf16x8*)(bbase + (size_t)n * 16 * C_ + k1);
      }
#pragma unroll
      for (int n = 0; n < 8; ++n) {
        acc[0][n] = __builtin_amdgcn_mfma_f32_16x16x32_bf16(ca0, cbf[n],
                                                            acc[0][n], 0, 0, 0);
        acc[1][n] = __builtin_amdgcn_mfma_f32_16x16x32_bf16(ca1, cbf[n],
                                                            acc[1][n], 0, 0, 0);
      }
      if (ks < 23) {
        ca0 = na0;
        ca1 = na1;
#pragma unroll
        for (int n = 0; n < 8; ++n) cbf[n] = nbf[n];
      }
    }

#pragma unroll
    for (int m = 0; m < 2; ++m) {
#pragma unroll
      for (int r = 0; r < 4; ++r) {
        unsigned keys[8];
#pragma unroll
        for (int n = 0; n < 8; ++n) {
          int code = code0 + n * 16;
          float d = fmaf(-2.0f, acc[m][n][r], norms_s[code]);
          keys[n] = (fmono(d) & 0xFFFFF800u) | (unsigned)code;
        }
        unsigned win[3];
#pragma unroll
        for (int rnd = 0; rnd < 3; ++rnd) {
          unsigned mn = keys[0];
#pragma unroll
          for (int n = 1; n < 8; ++n) mn = min(mn, keys[n]);
          mn = min(mn, (unsigned)__shfl_xor((int)mn, 1));
          mn = min(mn, (unsigned)__shfl_xor((int)mn, 2));
          mn = min(mn, (unsigned)__shfl_xor((int)mn, 4));
          mn = min(mn, (unsigned)__shfl_xor((int)mn, 8));
          win[rnd] = mn;
#pragma unroll
          for (int n = 0; n < 8; ++n)
            if (keys[n] == mn) keys[n] = 0xFFFFFFFFu;
        }
        if (col == 0) {
          int token = m * 16 + quad * 4 + r;
          unsigned* cp = &cands[token][chunk * 12 + wv * 3];
          cp[0] = win[0];
          cp[1] = win[1];
          cp[2] = win[2];
        }
      }
    }
  }
  __syncthreads();

  if (tid < 32) {
    unsigned best[6];
#pragma unroll
    for (int j = 0; j < 6; ++j) best[j] = 0xFFFFFFFFu;
    for (int s = 0; s < 48; ++s) {
      unsigned v = cands[tid][s];
      if (v < best[5]) {
        best[5] = v;
#pragma unroll
        for (int j = 5; j > 0; --j) {
          if (best[j] < best[j - 1]) {
            unsigned t = best[j];
            best[j] = best[j - 1];
            best[j - 1] = t;
          }
        }
      }
    }
#pragma unroll
    for (int j = 0; j < 6; ++j) rcode[tid][j] = (int)(best[j] & 0x7FFu);
  }
  __syncthreads();

  if (tid < 192) {
    int t = tid / 6;
    int j = tid - t * 6;
    int code = rcode[t][j];
    const float* xr = x + (tok0 + t) * (size_t)C_;
    const float* cr = cb + (size_t)code * C_;
    double s = 0.0;
    for (int c = 0; c < C_; c += 4) {
      float4 xa = *(const float4*)(xr + c);
      float4 ca = *(const float4*)(cr + c);
      s = fma((double)xa.x, (double)ca.x, s);
      s = fma((double)xa.y, (double)ca.y, s);
      s = fma((double)xa.z, (double)ca.z, s);
      s = fma((double)xa.w, (double)ca.w, s);
    }
    rd[t][j] = fma(-2.0, s, norms64[code]);
  }
  __syncthreads();

  if (tid < 32) {
    double bv = rd[tid][0];
    int bi = rcode[tid][0];
#pragma unroll
    for (int j = 1; j < 6; ++j) {
      double v = rd[tid][j];
      int i0 = rcode[tid][j];
      if (v < bv || (v == bv && i0 < bi)) {
        bv = v;
        bi = i0;
      }
    }
    out_idx[tok0 + tid] = bi;
  }
}

// ---------------------------------------------------------------------------
// Kernel E: per-batch softmax over att = ac[idx[l]] + fused output.
// 1024 threads (16 waves/CU) to hide the cb-gather latency.
// ---------------------------------------------------------------------------
__global__ __launch_bounds__(1024) void epilogue_kernel(
    const float* __restrict__ x, const float* __restrict__ cb,
    const float* __restrict__ ac, const int* __restrict__ idx,
    float* __restrict__ out, float* __restrict__ out_idx) {
  __shared__ float att[256];
  __shared__ float red[256];
  __shared__ int ids[L_];
  int b = blockIdx.x;
  int tid = threadIdx.x;

  float e = 0.0f;
  if (tid < 256) {
    float a = -1e30f;
    if (tid < L_) {
      int myid = idx[b * L_ + tid];
      ids[tid] = myid;
      a = ac[myid];
    }
    att[tid] = a;
    red[tid] = a;
  }
  __syncthreads();
  for (int s = 128; s > 0; s >>= 1) {
    if (tid < s) red[tid] = fmaxf(red[tid], red[tid + s]);
    __syncthreads();
  }
  float mx = red[0];
  __syncthreads();
  if (tid < 256) {
    e = (tid < L_) ? expf(att[tid] - mx) : 0.0f;
    red[tid] = e;
  }
  __syncthreads();
  for (int s = 128; s > 0; s >>= 1) {
    if (tid < s) red[tid] += red[tid + s];
    __syncthreads();
  }
  float sum = red[0];
  __syncthreads();
  if (tid < 256) att[tid] = e / sum;
  __syncthreads();

  const float4* xin = (const float4*)(x + (size_t)b * L_ * C_);
  float4* o = (float4*)(out + (size_t)b * L_ * C_);
  for (int i = tid; i < L_ * (C_ / 4); i += 1024) {
    int l = i / (C_ / 4);
    int c4 = i - l * (C_ / 4);
    const float4* crow = (const float4*)(cb + (size_t)ids[l] * C_);
    float4 xv = xin[i];
    float4 cv = crow[c4];
    float mk = att[l];
    float4 ov;
    ov.x = cv.x + xv.x * mk;
    ov.y = cv.y + xv.y * mk;
    ov.z = cv.z + xv.z * mk;
    ov.w = cv.w + xv.w * mk;
    o[i] = ov;
  }
  if (tid < L_) out_idx[b * L_ + tid] = (float)ids[tid];
}

// ---------------------------------------------------------------------------
extern "C" void kernel_launch(void* const* d_in, const int* in_sizes, int n_in,
                              void* d_out, int out_size, void* d_ws,
                              size_t ws_size, hipStream_t stream) {
  const float* in_feas = (const float*)d_in[0];   // [B,L,C] f32
  const float* cb = (const float*)d_in[1];        // [K,C]   f32
  const float* attw = (const float*)d_in[2];      // [1,C,3] f32

  // workspace layout
  char* ws = (char*)d_ws;
  size_t off = 0;
  unsigned short* cbb = (unsigned short*)(ws + off); off += 3145728;
  double* norms64 = (double*)(ws + off);           off += 16384;
  float* norms32 = (float*)(ws + off);             off += 8192;
  float* ac = (float*)(ws + off);                  off += 8192;
  int* idx = (int*)(ws + off);                     off += 200704;
  size_t base = off;                                // 3,379,200
  unsigned short* xb = (unsigned short*)(ws + off); off += (size_t)BL_ * C_ * 2;
  unsigned* ws_cand = (unsigned*)(ws + off);        off += (size_t)BL_ * 96 * 4;
  size_t need_full = off;                           // ~99.7 MB

  float* out = (float*)d_out;                      // out_feas [B,L,C]
  float* out_idx = out + (size_t)B_ * L_ * C_;     // idx map as float [B,H,W]

  precompute_kernel<<<K_ / 4, 256, 0, stream>>>(cb, attw, cbb, norms64,
                                                norms32, ac);
  if (ws_size >= need_full) {
    convert_kernel<<<BL_ * C_ / 4 / 256, 256, 0, stream>>>(in_feas, xb);
    // 1568 blocks = (BL/256) * (K/256) = 196 * 8
    phase1_kernel<<<dim3((BL_ / 256) * (K_ / 256)), 512, 0, stream>>>(
        xb, cbb, norms32, ws_cand);
    phase2_kernel<<<BL_ / 32, 768, 0, stream>>>(in_feas, cb, ws_cand, norms64,
                                                idx);
  } else {
    argmin_fallback<<<BL_ / 32, 256, 0, stream>>>(in_feas, cb, cbb, norms64,
                                                  norms32, idx);
  }
  epilogue_kernel<<<B_, 1024, 0, stream>>>(in_feas, cb, ac, idx, out, out_idx);
  (void)base;
}